// Round 1
// baseline (513.245 us; speedup 1.0000x reference)
//
#include <hip/hip_runtime.h>
#include <math.h>
#include <stdint.h>

// Problem constants
#define BB   32     // batch
#define HB   16     // batch per block (b-split: 2 blocks per n-group)
#define NN   2048   // input capsules
#define KK   16     // input dim
#define CC   32     // output capsules
#define DD   32     // capsule dim
#define NCOL 1024   // CC*DD
#define NPB  16     // n per block -> 128 n-groups x 2 b-halves = 256 blocks (1/CU)
#define WT   (KK * NCOL)          // 16384 floats = one 64 KB W tile
#define OSZ  (BB * NCOL)          // 32768 floats = one full o/partial image
#define NGRP (NN / NPB)           // 128 partial images
#define NSLICE 16                 // reduce tree fan-in stage 1: 128 -> 16

// async global->LDS. Global addr is per-lane; LDS dest must be the
// WAVE-UNIFORM base — HW writes lane i's 16 B at base + 16*i.
__device__ __forceinline__ void dma16(const float* g, const float* l) {
    __builtin_amdgcn_global_load_lds(
        (const __attribute__((address_space(1))) void*)(uintptr_t)g,
        (__attribute__((address_space(3))) void*)(uintptr_t)l,
        16, 0, 0);
}

// One routing iteration, fused. Per n:
//   U[b,col] = sum_k u[b,n,k] * W[n,k,col]; logit[b,c] = <U, onorm>;
//   softmax over caps; opart += c*U.
// R3/R4 lesson: the compiler pins 1024-thread blocks at 64 VGPR -> DESIGN for
// 64 VGPR: b-split across 2 blocks (16 b each), 16+16 per-thread accumulators.
// R5 (this round): the single-buffered W tile serialized the 64 KB/iter DMA
// against barrier C with only softmax (~100ns) as overlap -> HBM duty ~30%,
// stage 3.2x over its BW floor. Fix: DOUBLE-BUFFER W (2x64 KB LDS) and issue
// the prefetch at the TOP of the iteration so the whole accU FMA phase covers
// it; __syncthreads at B drains the residual. 148 KB LDS -> 1 block/CU, so
// NPB 8->16 keeps the grid at 256 blocks = 1/CU in a single round, and
// halves the partial-image count (128 groups -> less part traffic).
__global__ __launch_bounds__(1024)
void caps_stage(const float* __restrict__ u, const float* __restrict__ W,
                const float* __restrict__ onorm, float* __restrict__ part)
{
    __shared__ float Wt[2][WT];              // 128 KB double-buffered W tile
    __shared__ float ush[NPB * KK * HB];     // 16 KB: [n][k][b] all 16 n's
    __shared__ float logit_sh[HB * CC];      // 2 KB
    __shared__ float c_sh[HB * CC];          // 2 KB

    const int tid  = threadIdx.x;
    const int wave = tid >> 6;
    const int lane = tid & 63;
    const int bg = tid >> 8;          // 0..3 -> 4 local b's each
    const int cq = tid & 255;         // col-quad 0..255
    const int i0 = cq >> 3;           // capsule 0..31
    const int jq = cq & 7;            // d-quad
    const int b0 = bg << 2;           // local b base
    const int c0 = cq << 2;           // col base

    const int ngrp  = blockIdx.x >> 1;
    const int bhalf = blockIdx.x & 1;
    const int n0    = ngrp * NPB;
    const int bbase = bhalf * HB;     // global b offset

    const int woff = wave << 10;      // wave * 1024 floats (4 KB chunk)
    const int loff = lane << 2;       // lane * 4 floats

    // DMA one n's 64 KB W tile into dst: 16 waves x 4 x 16B/lane
    auto dma_tile = [&](int n, float* dst) {
        const float* g = W + (size_t)n * WT + woff + loff;
        const float* l = dst + woff;  // wave-uniform LDS base (no loff!)
#pragma unroll
        for (int j = 0; j < 4; ++j)
            dma16(g + j * 256, l + j * 256);
    };

    // prologue: W tile n0 -> buf0 + ALL u for this block (16 KB, [n][k][b])
    dma_tile(n0, Wt[0]);
    for (int idx = tid; idx < NPB * KK * HB; idx += 1024) {
        const int n = idx >> 8, rem = idx & 255, k = rem >> 4, b = rem & 15;
        ush[idx] = u[(size_t)(bbase + b) * (NN * KK) + (size_t)(n0 + n) * KK + k];
    }
    __syncthreads();   // drains prologue DMA + ush writes

    float opart[4][4];
#pragma unroll
    for (int bb = 0; bb < 4; ++bb)
#pragma unroll
        for (int m = 0; m < 4; ++m) opart[bb][m] = 0.f;

    for (int nn = 0; nn < NPB; ++nn) {
        // issue next tile's DMA FIRST so the whole compute phase hides it.
        // WAR-safe: all reads of Wt[(nn+1)&1] (done in iter nn-1's compute)
        // were ordered before barrier B(nn-1) < C(nn-1) < here.
        if (nn + 1 < NPB)
            dma_tile(n0 + nn + 1, Wt[(nn + 1) & 1]);

        const float* Wcur = Wt[nn & 1];      // resident since B of prev iter
        const float* un = &ush[nn << 8];

        float accU[4][4];
#pragma unroll
        for (int bb = 0; bb < 4; ++bb)
#pragma unroll
            for (int m = 0; m < 4; ++m) accU[bb][m] = 0.f;

#pragma unroll
        for (int k = 0; k < KK; ++k) {
            const float4 w  = *(const float4*)&Wcur[k * NCOL + c0];
            const float4 ub = *(const float4*)&un[(k << 4) + b0];  // u[b0..b0+3][k]
            accU[0][0] = fmaf(ub.x, w.x, accU[0][0]);
            accU[0][1] = fmaf(ub.x, w.y, accU[0][1]);
            accU[0][2] = fmaf(ub.x, w.z, accU[0][2]);
            accU[0][3] = fmaf(ub.x, w.w, accU[0][3]);
            accU[1][0] = fmaf(ub.y, w.x, accU[1][0]);
            accU[1][1] = fmaf(ub.y, w.y, accU[1][1]);
            accU[1][2] = fmaf(ub.y, w.z, accU[1][2]);
            accU[1][3] = fmaf(ub.y, w.w, accU[1][3]);
            accU[2][0] = fmaf(ub.z, w.x, accU[2][0]);
            accU[2][1] = fmaf(ub.z, w.y, accU[2][1]);
            accU[2][2] = fmaf(ub.z, w.z, accU[2][2]);
            accU[2][3] = fmaf(ub.z, w.w, accU[2][3]);
            accU[3][0] = fmaf(ub.w, w.x, accU[3][0]);
            accU[3][1] = fmaf(ub.w, w.y, accU[3][1]);
            accU[3][2] = fmaf(ub.w, w.z, accU[3][2]);
            accU[3][3] = fmaf(ub.w, w.w, accU[3][3]);
        }

        // ---- logits: dot with onorm (L2-resident), reduce over jq lanes ----
        float lp[4];
#pragma unroll
        for (int bb = 0; bb < 4; ++bb) {
            const float4 on4 = *(const float4*)(
                onorm + ((size_t)(bbase + b0 + bb) * CC + i0) * DD + (jq << 2));
            float p = accU[bb][0] * on4.x + accU[bb][1] * on4.y
                    + accU[bb][2] * on4.z + accU[bb][3] * on4.w;
            p += __shfl_xor(p, 1);
            p += __shfl_xor(p, 2);
            p += __shfl_xor(p, 4);
            lp[bb] = p;
        }
        if (jq == 0) {
#pragma unroll
            for (int bb = 0; bb < 4; ++bb)
                logit_sh[(b0 + bb) * CC + i0] = lp[bb];
        }
        __syncthreads();   // (B) logits ready; drains the prefetch residual

        // ---- softmax over capsules: 512 threads, (b = tid>>5, cap = tid&31) ----
        if (tid < HB * CC) {
            const int b  = tid >> 5;
            const int ii = tid & 31;
            float l = logit_sh[b * CC + ii];
            float mx = l;
#pragma unroll
            for (int msk = 16; msk >= 1; msk >>= 1)
                mx = fmaxf(mx, __shfl_xor(mx, msk));
            const float e = __expf(l - mx);
            float sm = e;
#pragma unroll
            for (int msk = 16; msk >= 1; msk >>= 1)
                sm += __shfl_xor(sm, msk);
            c_sh[b * CC + ii] = e / sm;
        }
        __syncthreads();   // (C) c ready

        // ---- opart += c * U ----
#pragma unroll
        for (int bb = 0; bb < 4; ++bb) {
            const float cc = c_sh[(b0 + bb) * CC + i0];
#pragma unroll
            for (int m = 0; m < 4; ++m)
                opart[bb][m] = fmaf(cc, accU[bb][m], opart[bb][m]);
        }
    }

    // flush partials, coalesced float4 stores (this block's 16-b half)
    float* my = part + (size_t)ngrp * OSZ + (size_t)bbase * NCOL;
#pragma unroll
    for (int bb = 0; bb < 4; ++bb) {
        float4 v;
        v.x = opart[bb][0]; v.y = opart[bb][1];
        v.z = opart[bb][2]; v.w = opart[bb][3];
        *(float4*)&my[(b0 + bb) * NCOL + c0] = v;
    }
}

// Level-1 reduce: 128 partial images -> NSLICE slice images (8 each).
__global__ __launch_bounds__(256) void caps_reduce1(
    const float* __restrict__ part, float* __restrict__ ws2)
{
    const int gid   = blockIdx.x * 256 + threadIdx.x;     // 0..131071
    const int slice = gid >> 13;                          // 0..15
    const int q     = gid & 8191;                         // col-quad
    float4 acc = make_float4(0.f, 0.f, 0.f, 0.f);
    const float* p = part + ((size_t)slice * 8) * OSZ + (q << 2);
#pragma unroll
    for (int j = 0; j < 8; ++j) {
        const float4 v = *(const float4*)(p + (size_t)j * OSZ);
        acc.x += v.x; acc.y += v.y; acc.z += v.z; acc.w += v.w;
    }
    *(float4*)(ws2 + ((size_t)slice << 15) + ((size_t)q << 2)) = acc;
}

// Level-2 reduce + row op. mode 0: l2-normalize. mode 1: squash.
__global__ __launch_bounds__(256) void caps_reduce2(
    const float* __restrict__ ws2, float* __restrict__ dst, int mode)
{
    const int q = blockIdx.x * 256 + threadIdx.x;         // 0..8191
    float4 acc = make_float4(0.f, 0.f, 0.f, 0.f);
#pragma unroll
    for (int s = 0; s < NSLICE; ++s) {
        const float4 v = *(const float4*)(ws2 + ((size_t)s << 15) + (q << 2));
        acc.x += v.x; acc.y += v.y; acc.z += v.z; acc.w += v.w;
    }
    float s2 = acc.x * acc.x + acc.y * acc.y + acc.z * acc.z + acc.w * acc.w;
    s2 += __shfl_xor(s2, 1);
    s2 += __shfl_xor(s2, 2);
    s2 += __shfl_xor(s2, 4);
    float scale;
    if (mode == 0) {
        scale = rsqrtf(fmaxf(s2, 1e-12f));
    } else {
        scale = (s2 / (1.f + s2)) / sqrtf(s2 + 1e-7f);
    }
    float4 o;
    o.x = acc.x * scale; o.y = acc.y * scale;
    o.z = acc.z * scale; o.w = acc.w * scale;
    *(float4*)(dst + ((size_t)q << 2)) = o;
}

extern "C" void kernel_launch(void* const* d_in, const int* in_sizes, int n_in,
                              void* d_out, int out_size, void* d_ws, size_t ws_size,
                              hipStream_t stream)
{
    const float* u = (const float*)d_in[0];   // (32, 2048, 16)
    const float* W = (const float*)d_in[1];   // (2048, 16, 1024)
    float* out = (float*)d_out;               // (32, 32, 32)

    // ws layout: part (128*32768 fl = 16 MB) | ws2 (2 MB) | onorm (128 KB)
    float* part  = (float*)d_ws;
    float* ws2   = part + (size_t)NGRP * OSZ;
    float* onorm = ws2 + (size_t)NSLICE * OSZ;

    // onorm = 0 => logits 0 => softmax uniform 1/32 (exactly iteration 0)
    hipMemsetAsync(onorm, 0, (size_t)OSZ * sizeof(float), stream);

    for (int it = 0; it < 3; ++it) {
        caps_stage<<<2 * NGRP, 1024, 0, stream>>>(u, W, onorm, part);
        caps_reduce1<<<512, 256, 0, stream>>>(part, ws2);
        if (it < 2)
            caps_reduce2<<<32, 256, 0, stream>>>(ws2, onorm, 0);  // l2-normalize
        else
            caps_reduce2<<<32, 256, 0, stream>>>(ws2, out, 1);    // squash -> d_out
    }
}